// Round 5
// baseline (330.318 us; speedup 1.0000x reference)
//
#include <hip/hip_runtime.h>
#include <stdint.h>

typedef __bf16 bf16;
typedef __bf16 bf16x8 __attribute__((ext_vector_type(8)));
typedef __bf16 bf16x4 __attribute__((ext_vector_type(4)));
typedef float  f32x4  __attribute__((ext_vector_type(4)));

#define T_SEQ  2048
#define NHEAD  16
#define DHEAD  128
#define DMODEL 2048
#define NQKV   3072   // 2048 Q | 512 K | 512 V per row
#define UNROLL _Pragma("unroll")

__device__ __forceinline__ void gload_lds16(const void* g, void* l) {
  __builtin_amdgcn_global_load_lds(
      (const __attribute__((address_space(1))) uint32_t*)g,
      (__attribute__((address_space(3))) uint32_t*)l, 16, 0, 0);
}

// ---------------- fp32 -> bf16 cast (x) ----------------
__global__ void k_cvt(const float* __restrict__ in, bf16* __restrict__ out) {
  int i = (blockIdx.x * 256 + threadIdx.x) * 4;
  float4 v = *(const float4*)(in + i);
  bf16x4 o = { (bf16)v.x, (bf16)v.y, (bf16)v.z, (bf16)v.w };
  *(bf16x4*)(out + i) = o;
}

// ---------------- W (K x N fp32) -> WT (N x K bf16) ----------------
__global__ __launch_bounds__(256) void k_twt(const float* __restrict__ W,
                                             bf16* __restrict__ WT, int K, int N) {
  __shared__ float t[64][65];
  int k0 = blockIdx.x * 64, n0 = blockIdx.y * 64;
  int r4 = threadIdx.x >> 6, c = threadIdx.x & 63;
#pragma unroll
  for (int i = 0; i < 16; i++) {
    int r = i * 4 + r4;
    t[r][c] = W[(size_t)(k0 + r) * N + n0 + c];
  }
  __syncthreads();
#pragma unroll
  for (int i = 0; i < 16; i++) {
    int r = i * 4 + r4;
    WT[(size_t)(n0 + r) * K + k0 + c] = (bf16)t[c][r];
  }
}

// ---------------- V pre-transpose: QKV V-cols -> Vtg[(b*4+kvh)*128 + d][t] ----
__global__ __launch_bounds__(256) void k_vt(const bf16* __restrict__ QKV,
                                            bf16* __restrict__ Vtg) {
  __shared__ bf16 t[64][65];
  const int t0 = blockIdx.x * 64, d0 = blockIdx.y * 64;
  const int g = blockIdx.z, b = g >> 2, kvh = g & 3;
  const bf16* src = QKV + (size_t)b * T_SEQ * NQKV + 2560 + kvh * DHEAD;
  bf16* dst = Vtg + ((size_t)(b * 4 + kvh) * 128 + d0) * T_SEQ + t0;
  const int r4 = threadIdx.x >> 6, c = threadIdx.x & 63;
#pragma unroll
  for (int i = 0; i < 16; i++) {
    int r = i * 4 + r4;
    t[r][c] = src[(size_t)(t0 + r) * NQKV + d0 + c];
  }
  __syncthreads();
#pragma unroll
  for (int i = 0; i < 16; i++) {
    int r = i * 4 + r4;
    dst[(size_t)r * T_SEQ + c] = t[c][r];
  }
}

// ---------------- GEMM: C[M,N] = A[M,K] * BT[N,K]^T  (m97 + XCD swizzle) --------
template<bool F32OUT>
__global__ __launch_bounds__(256) void k_gemm(const bf16* __restrict__ A,
                                              const bf16* __restrict__ BT,
                                              void* __restrict__ C,
                                              int M, int N, int K) {
  __shared__ __align__(16) bf16 As[128 * 64];
  __shared__ __align__(16) bf16 Bs[128 * 64];
  const int nwg = gridDim.x * gridDim.y;
  const int orig = blockIdx.y * gridDim.x + blockIdx.x;
  const int tile = (orig & 7) * (nwg >> 3) + (orig >> 3);   // nwg % 8 == 0
  const int m0 = (tile % gridDim.x) * 128, n0 = (tile / gridDim.x) * 128;
  const int tid = threadIdx.x;
  const int lane = tid & 63, w = tid >> 6;
  const int wr = w >> 1, wc = w & 1;
  const int l15 = lane & 15, lg = lane >> 4;
  f32x4 acc[4][4] = {};

  const int rA = w * 32 + (lane >> 3);
  const int cA = (lane & 7) * 8;
  const bf16* gA = A  + (size_t)(m0 + rA) * K + cA;
  const bf16* gB = BT + (size_t)(n0 + rA) * K + cA;

  for (int k0 = 0; k0 < K; k0 += 64) {
    __syncthreads();
#pragma unroll
    for (int i = 0; i < 4; i++) {
      gload_lds16(gA + (size_t)i * 8 * K + k0, As + (w * 4 + i) * 512);
      gload_lds16(gB + (size_t)i * 8 * K + k0, Bs + (w * 4 + i) * 512);
    }
    __syncthreads();
#pragma unroll
    for (int kk = 0; kk < 2; kk++) {
      bf16x8 af[4], bfr[4];
#pragma unroll
      for (int m = 0; m < 4; m++)
        af[m] = *(const bf16x8*)(As + (wr * 64 + m * 16 + l15) * 64 + kk * 32 + lg * 8);
#pragma unroll
      for (int n = 0; n < 4; n++)
        bfr[n] = *(const bf16x8*)(Bs + (wc * 64 + n * 16 + l15) * 64 + kk * 32 + lg * 8);
#pragma unroll
      for (int m = 0; m < 4; m++)
#pragma unroll
        for (int n = 0; n < 4; n++)
          acc[m][n] = __builtin_amdgcn_mfma_f32_16x16x32_bf16(af[m], bfr[n], acc[m][n], 0, 0, 0);
    }
  }
  const int r0 = m0 + wr * 64 + lg * 4;
  const int c0 = n0 + wc * 64 + l15;
#pragma unroll
  for (int m = 0; m < 4; m++)
#pragma unroll
    for (int n = 0; n < 4; n++)
#pragma unroll
      for (int i = 0; i < 4; i++) {
        size_t idx = (size_t)(r0 + m * 16 + i) * N + (c0 + n * 16);
        if (F32OUT) ((float*)C)[idx] = acc[m][n][i];
        else        ((bf16*)C)[idx]  = (bf16)acc[m][n][i];
      }
}

// ---------------- in-place RoPE on QKV cols [0,2560) ----------------
__global__ void k_rope(bf16* __restrict__ QKV) {
  const float L2B = 0.20762050593046007f;  // log2(10000)/64
  int tid = blockIdx.x * 256 + threadIdx.x;
  int row = tid / 320;
  int c8 = (tid - row * 320) * 8;
  int t = row & (T_SEQ - 1);
  bf16* p = QKV + (size_t)row * NQKV + c8;
  bf16x8 v = *(const bf16x8*)p;
  int ib = (c8 & 127) >> 1;
  bf16x8 o;
#pragma unroll
  for (int m = 0; m < 4; m++) {
    float inv = exp2f(-(float)(ib + m) * L2B);
    float ang = (float)t * inv;
    float cs, sn;
    __sincosf(ang, &sn, &cs);
    float x1 = (float)v[2 * m], x2 = (float)v[2 * m + 1];
    o[2 * m]     = (bf16)(x1 * cs - x2 * sn);
    o[2 * m + 1] = (bf16)(x1 * sn + x2 * cs);
  }
  *(bf16x8*)p = o;
}

// ---------------- flash attention (causal, GQA), 1 q-tile/block, 3 blocks/CU ----
// Q pre-scaled by (1/sqrt(Dh))*log2(e); exp2 softmax; MFMA row-sum; defer-max.
// Single-buffered K/V (gload_lds, 2 barriers/tile); Ps stride-136B (conflict-free).
#define COMPUTE(qreg, o, mrow, lrow, qt_this, kt) do {                                    \
    f32x4 s_[4] = {};                                                                     \
    const char* ks_ = (const char*)Ks;                                                    \
    __builtin_amdgcn_s_setprio(1);                                                        \
    UNROLL for (int kk = 0; kk < 4; kk++)                                                 \
      UNROLL for (int n = 0; n < 4; n++) {                                                \
        int row_ = n * 16 + l15;                                                          \
        int cb_ = (kk * 64 + lg * 16) ^ ((row_ & 7) << 4);                                \
        bf16x8 kf_ = *(const bf16x8*)(ks_ + row_ * 256 + cb_);                            \
        s_[n] = __builtin_amdgcn_mfma_f32_16x16x32_bf16(qreg[kk], kf_, s_[n], 0, 0, 0);   \
      }                                                                                   \
    __builtin_amdgcn_s_setprio(0);                                                        \
    if ((kt) == (qt_this)) {                                                              \
      UNROLL for (int n = 0; n < 4; n++)                                                  \
        UNROLL for (int i = 0; i < 4; i++)                                                \
          if ((kt) * 64 + n * 16 + l15 > (qt_this) * 64 + w * 16 + lg * 4 + i)            \
            s_[n][i] = -1e30f;                                                            \
    }                                                                                     \
    float pm_[4];                                                                         \
    UNROLL for (int i = 0; i < 4; i++)                                                    \
      pm_[i] = fmaxf(fmaxf(s_[0][i], s_[1][i]), fmaxf(s_[2][i], s_[3][i]));               \
    UNROLL for (int i = 0; i < 4; i++) {                                                  \
      float v_ = pm_[i];                                                                  \
      v_ = fmaxf(v_, __shfl_xor(v_, 1));                                                  \
      v_ = fmaxf(v_, __shfl_xor(v_, 2));                                                  \
      v_ = fmaxf(v_, __shfl_xor(v_, 4));                                                  \
      v_ = fmaxf(v_, __shfl_xor(v_, 8));                                                  \
      pm_[i] = v_;                                                                        \
    }                                                                                     \
    bool ok_ = true;                                                                      \
    UNROLL for (int i = 0; i < 4; i++) ok_ = ok_ && (pm_[i] <= mrow[i] + 8.0f);           \
    if (!__all(ok_)) {                                                                    \
      UNROLL for (int i = 0; i < 4; i++) {                                                \
        float mn_ = fmaxf(mrow[i], pm_[i]);                                               \
        float al_ = __builtin_amdgcn_exp2f(mrow[i] - mn_);                                \
        mrow[i] = mn_;                                                                    \
        lrow[i] *= al_;                                                                   \
        UNROLL for (int n = 0; n < 8; n++) o[n][i] *= al_;                                \
      }                                                                                   \
    }                                                                                     \
    UNROLL for (int n = 0; n < 4; n++)                                                    \
      UNROLL for (int i = 0; i < 4; i++)                                                  \
        Ps[w][lg * 4 + i][n * 16 + l15] =                                                 \
            (bf16)__builtin_amdgcn_exp2f(s_[n][i] - mrow[i]);                             \
    f32x4 rs_ = {};                                                                       \
    const char* vs_ = (const char*)Vs;                                                    \
    __builtin_amdgcn_s_setprio(1);                                                        \
    UNROLL for (int kc = 0; kc < 2; kc++) {                                               \
      bf16x8 pa_ = *(const bf16x8*)(&Ps[w][l15][kc * 32 + lg * 8]);                       \
      rs_ = __builtin_amdgcn_mfma_f32_16x16x32_bf16(pa_, ones_, rs_, 0, 0, 0);            \
      UNROLL for (int n = 0; n < 8; n++) {                                                \
        int d_ = n * 16 + l15;                                                            \
        bf16x8 vf_ = *(const bf16x8*)(vs_ + d_ * 128 + ((((kc << 2) + lg) ^ (d_ & 7)) << 4)); \
        o[n] = __builtin_amdgcn_mfma_f32_16x16x32_bf16(pa_, vf_, o[n], 0, 0, 0);          \
      }                                                                                   \
    }                                                                                     \
    __builtin_amdgcn_s_setprio(0);                                                        \
    UNROLL for (int i = 0; i < 4; i++) lrow[i] += rs_[i];                                 \
  } while (0)

__global__ __launch_bounds__(256) void k_flash(const bf16* __restrict__ QKV,
                                               const bf16* __restrict__ Vtg,
                                               bf16* __restrict__ AO) {
  __shared__ __align__(16) bf16 Ks[64 * 128];   // [kv row]*256B, chunk XOR (row&7)
  __shared__ __align__(16) bf16 Vs[128 * 64];   // [d row]*128B,  chunk XOR (d&7)
  __shared__ __align__(16) bf16 Ps[4][16][68];  // stride 136B: conflict-free wr/rd
  const int qt = 31 - blockIdx.x;               // longest-first dispatch
  const int bh = blockIdx.y;
  const int b = bh >> 4, h = bh & 15, kvh = h >> 2;
  const int tid = threadIdx.x, lane = tid & 63, w = tid >> 6;
  const int l15 = lane & 15, lg = lane >> 4;
  const float qs = 0.12753102f;          // (1/sqrt(128)) * log2(e)

  bf16x8 qreg[4];
  {
    const size_t qo = (size_t)(b * T_SEQ + qt * 64 + w * 16 + l15) * NQKV + h * DHEAD;
    UNROLL for (int kk = 0; kk < 4; kk++) {
      bf16x8 a = *(const bf16x8*)(QKV + qo + kk * 32 + lg * 8);
      UNROLL for (int j = 0; j < 8; j++) a[j] = (bf16)((float)a[j] * qs);
      qreg[kk] = a;
    }
  }
  bf16x8 ones_;
  UNROLL for (int j = 0; j < 8; j++) ones_[j] = (bf16)1.0f;

  f32x4 o[8] = {};
  float mrow[4], lrow[4];
  UNROLL for (int i = 0; i < 4; i++) { mrow[i] = -1e30f; lrow[i] = 0.f; }

  const bf16* Kbase = QKV + (size_t)b * T_SEQ * NQKV + DMODEL + kvh * DHEAD;
  const bf16* Vbase = Vtg + (size_t)(b * 4 + kvh) * 128 * T_SEQ;

  auto issueK = [&](int kt) {
    UNROLL for (int i = 0; i < 4; i++) {
      int row = w * 16 + i * 4 + lg;
      int col = (l15 ^ (row & 7)) * 8;
      gload_lds16(Kbase + (size_t)(kt * 64 + row) * NQKV + col,
                  Ks + (w * 4 + i) * 512);
    }
  };
  auto issueV = [&](int kt) {
    UNROLL for (int i = 0; i < 4; i++) {
      int d = (w * 4 + i) * 8 + (lane >> 3);
      int u = lane & 7;
      gload_lds16(Vbase + (size_t)d * T_SEQ + kt * 64 + ((u ^ (d & 7)) * 8),
                  Vs + (w * 4 + i) * 512);
    }
  };

  issueK(0);
  issueV(0);
  __syncthreads();

  const int NT = qt + 1;
  for (int kt = 0; kt < NT; kt++) {
    COMPUTE(qreg, o, mrow, lrow, qt, kt);
    if (kt + 1 < NT) {
      __syncthreads();            // all reads of Ks/Vs done
      issueK(kt + 1);
      issueV(kt + 1);
      __syncthreads();            // staging landed (vmcnt drained at barrier)
    }
  }

  const size_t obase = (size_t)(b * T_SEQ + qt * 64 + w * 16 + lg * 4) * DMODEL + h * DHEAD + l15;
  UNROLL for (int i = 0; i < 4; i++) {
    float inv = 1.0f / lrow[i];
    UNROLL for (int n = 0; n < 8; n++)
      AO[obase + (size_t)i * DMODEL + n * 16] = (bf16)(o[n][i] * inv);
  }
}

extern "C" void kernel_launch(void* const* d_in, const int* in_sizes, int n_in,
                              void* d_out, int out_size, void* d_ws, size_t ws_size,
                              hipStream_t stream) {
  const float* x  = (const float*)d_in[0];
  const float* Wq = (const float*)d_in[1];
  const float* Wk = (const float*)d_in[2];
  const float* Wv = (const float*)d_in[3];
  const float* Wo = (const float*)d_in[4];
  char* ws = (char*)d_ws;
  bf16* xb  = (bf16*)ws;                                             // 4096x2048
  bf16* WT  = (bf16*)(ws + 16777216ull);                             // 3072x2048 (WqT|WkT|WvT)
  bf16* WoT = (bf16*)(ws + 16777216ull + 12582912ull);               // 2048x2048
  bf16* QKV = (bf16*)(ws + 16777216ull + 12582912ull + 8388608ull);  // 4096x3072
  bf16* AO  = (bf16*)(ws + 16777216ull + 12582912ull + 8388608ull + 25165824ull); // 4096x2048
  bf16* Vtg = WT;   // WT is dead after the QKV GEMM; reuse first 4 MB for V^T
  float* out = (float*)d_out;

  k_cvt<<<8192, 256, 0, stream>>>(x, xb);
  k_twt<<<dim3(32, 32), 256, 0, stream>>>(Wq, WT, 2048, 2048);
  k_twt<<<dim3(32, 8), 256, 0, stream>>>(Wk, WT + (size_t)2048 * 2048, 2048, 512);
  k_twt<<<dim3(32, 8), 256, 0, stream>>>(Wv, WT + (size_t)2560 * 2048, 2048, 512);
  k_twt<<<dim3(32, 32), 256, 0, stream>>>(Wo, WoT, 2048, 2048);
  k_gemm<false><<<dim3(32, 24), 256, 0, stream>>>(xb, WT, QKV, 4096, 3072, 2048);
  k_rope<<<5120, 256, 0, stream>>>(QKV);
  k_vt<<<dim3(32, 2, 8), 256, 0, stream>>>(QKV, Vtg);
  k_flash<<<dim3(32, 32), 256, 0, stream>>>(QKV, Vtg, AO);
  k_gemm<true><<<dim3(32, 16), 256, 0, stream>>>(AO, WoT, out, 4096, 2048, 2048);
}